// Round 2
// baseline (758.568 us; speedup 1.0000x reference)
//
#include <hip/hip_runtime.h>

#define OUT_DIM 4096
#define IN_DIM 4096
#define N_OUTLIERS 64
#define Q_IN (IN_DIM - N_OUTLIERS)   // 4032
#define M_TOT 8192                   // 4*2048 rows of input
#define K_TOT IN_DIM
#define N_TOT OUT_DIM

#define BM 128
#define BN 128
#define BK 64

using frag  = __attribute__((ext_vector_type(8))) short;   // 8 bf16 (4 VGPRs)
using f32x4 = __attribute__((ext_vector_type(4))) float;   // 4 fp32 acc

__device__ __forceinline__ unsigned short f2bf(float f) {
  unsigned int u = __float_as_uint(f);
  u += 0x7fff + ((u >> 16) & 1);          // RNE (normal values; inputs are finite)
  return (unsigned short)(u >> 16);
}

__device__ __forceinline__ void async16(const void* g, void* l) {
  __builtin_amdgcn_global_load_lds(
      (const __attribute__((address_space(1))) unsigned int*)g,
      (__attribute__((address_space(3))) unsigned int*)l,
      16, 0, 0);
}

// ---------------------------------------------------------------------------
// Kernel 1: build bf16 W[OUT][IN] = concat([w_noised, fp], axis=1)[:, inv_perm]
// grid: (IN_DIM/256, OUT_DIM), block 256. Gather reads L2-cached per row.
// ---------------------------------------------------------------------------
__global__ void build_w(const float* __restrict__ qw, const float* __restrict__ fpw,
                        const float* __restrict__ alpha, const float* __restrict__ noise,
                        const int* __restrict__ perm, unsigned short* __restrict__ W) {
  const int j = blockIdx.x * 256 + threadIdx.x;   // output column
  const int o = blockIdx.y;                       // output row
  const int c = perm[j];                          // source column
  const float a = alpha[o];
  float val;
  if (c < Q_IN) {
    const float w  = qw[o * Q_IN + c];
    const float nz = noise[o * Q_IN + c];
    const float t  = w + nz * 0.5f * (a * (1.0f / 7.0f));   // QMAX = 7
    val = (w <= -a) ? -a : t;
    val = (w >=  a) ?  a : val;
  } else {
    val = fpw[o * N_OUTLIERS + (c - Q_IN)];
  }
  W[(size_t)o * IN_DIM + j] = f2bf(val);
}

// ---------------------------------------------------------------------------
// Kernel 2: X f32 -> bf16, float4 vectorized grid-stride
// ---------------------------------------------------------------------------
__global__ void cvt_x(const float* __restrict__ x, unsigned short* __restrict__ y) {
  const int n4 = (M_TOT * K_TOT) / 4;
  const int stride = gridDim.x * blockDim.x;
  for (int i = blockIdx.x * blockDim.x + threadIdx.x; i < n4; i += stride) {
    float4 v = ((const float4*)x)[i];
    ushort4 o;
    o.x = f2bf(v.x); o.y = f2bf(v.y); o.z = f2bf(v.z); o.w = f2bf(v.w);
    ((ushort4*)y)[i] = o;
  }
}

// ---------------------------------------------------------------------------
// Kernel 3: C[M][N] = A[M][K] * B[N][K]^T + bias   (all bf16 in, f32 out)
// m97 structure: 128x128 tile, BK=64, 4 waves (2x2), 4x4 frags of 16x16x32.
// global_load_lds width=16 staging into linear LDS, 2 barriers per K-step.
// ---------------------------------------------------------------------------
__global__ __launch_bounds__(256) void gemm_bt(const unsigned short* __restrict__ A,
                                               const unsigned short* __restrict__ B,
                                               const float* __restrict__ bias,
                                               float* __restrict__ C) {
  __shared__ unsigned short sA[BM * BK];   // [128][64] row-major, 16 KB
  __shared__ unsigned short sB[BN * BK];   // [128][64] row-major, 16 KB

  const int tid = threadIdx.x;
  const int w   = tid >> 6;       // wave 0..3
  const int l   = tid & 63;

  const int bid = blockIdx.x;
  const int tm  = bid >> 5;       // N_TOT/BN = 32 tiles in n
  const int tn  = bid & 31;
  const int row0 = tm * BM;
  const int col0 = tn * BN;

  // --- staging geometry: wave w stages rows [w*32, w*32+32) of each tile ---
  // per issue: 64 lanes x 16B = 1024B = 8 rows of 128B. 4 issues per wave.
  const int sr = w * 32 + (l >> 3);        // global row within tile (+ i*8)
  const int sc = (l & 7) * 8;              // element column within BK
  const unsigned short* gA = A + (size_t)(row0 + sr) * K_TOT + sc;
  const unsigned short* gB = B + (size_t)(col0 + sr) * K_TOT + sc;
  unsigned short* lA = &sA[(w * 32) * BK]; // wave-uniform base; HW adds lane*16B
  unsigned short* lB = &sB[(w * 32) * BK];

  // --- compute geometry: wave (wr,wc) owns a 64x64 output sub-tile ---
  const int wr = w >> 1, wc = w & 1;
  const int ar = wr * 64 + (l & 15);       // A row in tile (+ mi*16)
  const int br = wc * 64 + (l & 15);       // B row (= output col) in tile (+ ni*16)
  const int ak = (l >> 4) * 8;             // k offset within 32-k step

  f32x4 acc[4][4] = {};

  for (int kt = 0; kt < K_TOT / BK; ++kt) {
    const int k0 = kt * BK;
#pragma unroll
    for (int i = 0; i < 4; ++i) {
      async16(gA + (size_t)i * 8 * K_TOT + k0, lA + i * 8 * BK);
      async16(gB + (size_t)i * 8 * K_TOT + k0, lB + i * 8 * BK);
    }
    __syncthreads();   // compiler drains vmcnt(0) before s_barrier

#pragma unroll
    for (int kk = 0; kk < BK / 32; ++kk) {
      frag a[4], b[4];
#pragma unroll
      for (int mi = 0; mi < 4; ++mi)
        a[mi] = *(const frag*)&sA[(ar + mi * 16) * BK + kk * 32 + ak];
#pragma unroll
      for (int ni = 0; ni < 4; ++ni)
        b[ni] = *(const frag*)&sB[(br + ni * 16) * BK + kk * 32 + ak];
#pragma unroll
      for (int mi = 0; mi < 4; ++mi)
#pragma unroll
        for (int ni = 0; ni < 4; ++ni)
          acc[mi][ni] = __builtin_amdgcn_mfma_f32_16x16x32_bf16(
              a[mi], b[ni], acc[mi][ni], 0, 0, 0);
    }
    __syncthreads();   // protect LDS before next stage
  }

  // --- epilogue: C/D layout col = lane&15, row = (lane>>4)*4 + reg ---
  float bv[4];
#pragma unroll
  for (int ni = 0; ni < 4; ++ni)
    bv[ni] = bias[col0 + wc * 64 + ni * 16 + (l & 15)];

#pragma unroll
  for (int mi = 0; mi < 4; ++mi) {
    const int r = row0 + wr * 64 + mi * 16 + (l >> 4) * 4;
#pragma unroll
    for (int ni = 0; ni < 4; ++ni) {
      const int c = col0 + wc * 64 + ni * 16 + (l & 15);
      float* p = C + (size_t)r * N_TOT + c;
#pragma unroll
      for (int i = 0; i < 4; ++i)
        p[(size_t)i * N_TOT] = acc[mi][ni][i] + bv[ni];
    }
  }
}

extern "C" void kernel_launch(void* const* d_in, const int* in_sizes, int n_in,
                              void* d_out, int out_size, void* d_ws, size_t ws_size,
                              hipStream_t stream) {
  const float* x     = (const float*)d_in[0];
  const float* qw    = (const float*)d_in[1];
  const float* fpw   = (const float*)d_in[2];
  const float* alpha = (const float*)d_in[3];
  const float* bias  = (const float*)d_in[4];
  const float* noise = (const float*)d_in[5];
  const int*   perm  = (const int*)d_in[6];
  float* out = (float*)d_out;

  unsigned short* Xb = (unsigned short*)d_ws;               // 67 MB bf16 X
  unsigned short* W  = Xb + (size_t)M_TOT * K_TOT;          // 33.5 MB bf16 W

  build_w<<<dim3(IN_DIM / 256, OUT_DIM), 256, 0, stream>>>(qw, fpw, alpha, noise, perm, W);
  cvt_x<<<4096, 256, 0, stream>>>(x, Xb);
  gemm_bt<<<(M_TOT / BM) * (N_TOT / BN), 256, 0, stream>>>(Xb, W, bias, out);
}

// Round 3
// 713.052 us; speedup vs baseline: 1.0638x; 1.0638x over previous
//
#include <hip/hip_runtime.h>

#define OUT_DIM 4096
#define IN_DIM 4096
#define N_OUTLIERS 64
#define Q_IN (IN_DIM - N_OUTLIERS)   // 4032
#define M_TOT 8192                   // 4*2048 rows of input
#define K_TOT IN_DIM
#define N_TOT OUT_DIM

#define BM 128
#define BN 128
#define BK 64

using frag  = __attribute__((ext_vector_type(8))) short;   // 8 bf16 (4 VGPRs)
using f32x4 = __attribute__((ext_vector_type(4))) float;   // 4 fp32 acc

__device__ __forceinline__ unsigned short f2bf(float f) {
  unsigned int u = __float_as_uint(f);
  u += 0x7fff + ((u >> 16) & 1);          // RNE
  return (unsigned short)(u >> 16);
}

__device__ __forceinline__ void async16(const void* g, void* l) {
  __builtin_amdgcn_global_load_lds(
      (const __attribute__((address_space(1))) unsigned int*)g,
      (__attribute__((address_space(3))) unsigned int*)l,
      16, 0, 0);
}

// ---------------------------------------------------------------------------
// Kernel 0: invert the column permutation. perm[j] = source col for out col j
// -> pos[c] = destination col for source col c.
// ---------------------------------------------------------------------------
__global__ void inv_perm_k(const int* __restrict__ perm, int* __restrict__ pos) {
  const int j = blockIdx.x * 256 + threadIdx.x;
  pos[perm[j]] = j;
}

// ---------------------------------------------------------------------------
// Kernel 1: build bf16 W. Thread = (row o, SOURCE col c): coalesced reads of
// qw/noise/fpw, scattered 2B write to W[o][pos[c]]. Scatter stays within the
// row's 8KB span -> L2 lines fill completely before writeback.
// ---------------------------------------------------------------------------
__global__ void build_w(const float* __restrict__ qw, const float* __restrict__ fpw,
                        const float* __restrict__ alpha, const float* __restrict__ noise,
                        const int* __restrict__ pos, unsigned short* __restrict__ W) {
  const int c = blockIdx.x * 256 + threadIdx.x;   // source column 0..4095
  const int o = blockIdx.y;                       // output row
  const float a = alpha[o];
  float val;
  if (c < Q_IN) {
    const float w  = qw[o * Q_IN + c];
    const float nz = noise[o * Q_IN + c];
    const float t  = w + nz * 0.5f * (a * (1.0f / 7.0f));   // QMAX = 7
    val = (w <= -a) ? -a : t;
    val = (w >=  a) ?  a : val;
  } else {
    val = fpw[o * N_OUTLIERS + (c - Q_IN)];
  }
  W[(size_t)o * IN_DIM + pos[c]] = f2bf(val);
}

// ---------------------------------------------------------------------------
// Kernel 2: X f32 -> bf16, float4 vectorized grid-stride
// ---------------------------------------------------------------------------
__global__ void cvt_x(const float* __restrict__ x, unsigned short* __restrict__ y) {
  const int n4 = (M_TOT * K_TOT) / 4;
  const int stride = gridDim.x * blockDim.x;
  for (int i = blockIdx.x * blockDim.x + threadIdx.x; i < n4; i += stride) {
    float4 v = ((const float4*)x)[i];
    ushort4 o;
    o.x = f2bf(v.x); o.y = f2bf(v.y); o.z = f2bf(v.z); o.w = f2bf(v.w);
    ((ushort4*)y)[i] = o;
  }
}

// ---------------------------------------------------------------------------
// Kernel 3: C[M][N] = A[M][K] * B[N][K]^T + bias   (bf16 in, f32 out)
// m97 structure + T1 bijective XCD swizzle (nwg=2048, %8==0).
// ---------------------------------------------------------------------------
__global__ __launch_bounds__(256) void gemm_bt(const unsigned short* __restrict__ A,
                                               const unsigned short* __restrict__ B,
                                               const float* __restrict__ bias,
                                               float* __restrict__ C) {
  __shared__ unsigned short sA[BM * BK];   // [128][64] row-major, 16 KB
  __shared__ unsigned short sB[BN * BK];

  const int tid = threadIdx.x;
  const int w   = tid >> 6;
  const int l   = tid & 63;

  // T1: XCD-aware remap. Block b runs on XCD b%8; give each XCD a contiguous
  // chunk of the tile space so neighboring tiles share L2-resident panels.
  const int nwg = (M_TOT / BM) * (N_TOT / BN);      // 2048
  const int swz = (blockIdx.x & 7) * (nwg >> 3) + (blockIdx.x >> 3);
  const int tm  = swz >> 5;       // N_TOT/BN = 32 tiles in n
  const int tn  = swz & 31;
  const int row0 = tm * BM;
  const int col0 = tn * BN;

  // --- staging: wave w stages rows [w*32, w*32+32); 4 issues x 1KB each ---
  const int sr = w * 32 + (l >> 3);
  const int sc = (l & 7) * 8;
  const unsigned short* gA = A + (size_t)(row0 + sr) * K_TOT + sc;
  const unsigned short* gB = B + (size_t)(col0 + sr) * K_TOT + sc;
  unsigned short* lA = &sA[(w * 32) * BK];
  unsigned short* lB = &sB[(w * 32) * BK];

  // --- compute: wave (wr,wc) owns a 64x64 output sub-tile ---
  const int wr = w >> 1, wc = w & 1;
  const int ar = wr * 64 + (l & 15);
  const int br = wc * 64 + (l & 15);
  const int ak = (l >> 4) * 8;

  f32x4 acc[4][4] = {};

  for (int kt = 0; kt < K_TOT / BK; ++kt) {
    const int k0 = kt * BK;
#pragma unroll
    for (int i = 0; i < 4; ++i) {
      async16(gA + (size_t)i * 8 * K_TOT + k0, lA + i * 8 * BK);
      async16(gB + (size_t)i * 8 * K_TOT + k0, lB + i * 8 * BK);
    }
    __syncthreads();

#pragma unroll
    for (int kk = 0; kk < BK / 32; ++kk) {
      frag a[4], b[4];
#pragma unroll
      for (int mi = 0; mi < 4; ++mi)
        a[mi] = *(const frag*)&sA[(ar + mi * 16) * BK + kk * 32 + ak];
#pragma unroll
      for (int ni = 0; ni < 4; ++ni)
        b[ni] = *(const frag*)&sB[(br + ni * 16) * BK + kk * 32 + ak];
#pragma unroll
      for (int mi = 0; mi < 4; ++mi)
#pragma unroll
        for (int ni = 0; ni < 4; ++ni)
          acc[mi][ni] = __builtin_amdgcn_mfma_f32_16x16x32_bf16(
              a[mi], b[ni], acc[mi][ni], 0, 0, 0);
    }
    __syncthreads();
  }

  // --- epilogue: C/D layout col = lane&15, row = (lane>>4)*4 + reg ---
  float bv[4];
#pragma unroll
  for (int ni = 0; ni < 4; ++ni)
    bv[ni] = bias[col0 + wc * 64 + ni * 16 + (l & 15)];

#pragma unroll
  for (int mi = 0; mi < 4; ++mi) {
    const int r = row0 + wr * 64 + mi * 16 + (l >> 4) * 4;
#pragma unroll
    for (int ni = 0; ni < 4; ++ni) {
      const int c = col0 + wc * 64 + ni * 16 + (l & 15);
      float* p = C + (size_t)r * N_TOT + c;
#pragma unroll
      for (int i = 0; i < 4; ++i)
        p[(size_t)i * N_TOT] = acc[mi][ni][i] + bv[ni];
    }
  }
}

extern "C" void kernel_launch(void* const* d_in, const int* in_sizes, int n_in,
                              void* d_out, int out_size, void* d_ws, size_t ws_size,
                              hipStream_t stream) {
  const float* x     = (const float*)d_in[0];
  const float* qw    = (const float*)d_in[1];
  const float* fpw   = (const float*)d_in[2];
  const float* alpha = (const float*)d_in[3];
  const float* bias  = (const float*)d_in[4];
  const float* noise = (const float*)d_in[5];
  const int*   perm  = (const int*)d_in[6];
  float* out = (float*)d_out;

  // ws layout: pos[4096] ints (16KB) | Xb bf16 (67MB) | W bf16 (33.5MB)
  int* pos = (int*)d_ws;
  unsigned short* Xb = (unsigned short*)((char*)d_ws + 16384);
  unsigned short* W  = Xb + (size_t)M_TOT * K_TOT;

  inv_perm_k<<<IN_DIM / 256, 256, 0, stream>>>(perm, pos);
  build_w<<<dim3(IN_DIM / 256, OUT_DIM), 256, 0, stream>>>(qw, fpw, alpha, noise, pos, W);
  cvt_x<<<4096, 256, 0, stream>>>(x, Xb);
  gemm_bt<<<(M_TOT / BM) * (N_TOT / BN), 256, 0, stream>>>(Xb, W, bias, out);
}